// Round 3
// baseline (157.470 us; speedup 1.0000x reference)
//
#include <hip/hip_runtime.h>

typedef unsigned short u16;
typedef float f32x4 __attribute__((ext_vector_type(4)));
typedef unsigned short u16x8 __attribute__((ext_vector_type(8)));
typedef unsigned short u16x4 __attribute__((ext_vector_type(4)));
typedef __bf16 bf16x8 __attribute__((ext_vector_type(8)));

union Frag { u16x8 u; bf16x8 b; };

#define DEVFN static __device__ __forceinline__

DEVFN u16 f2bf(float f) {
  unsigned u = __builtin_bit_cast(unsigned, f);
  u += 0x7FFFu + ((u >> 16) & 1u);
  return (u16)(u >> 16);
}
DEVFN float bf2f(u16 h) {
  return __builtin_bit_cast(float, ((unsigned)h) << 16);
}
DEVFN int bswz(int n, int k) { return k ^ ((((n >> 4) ^ n) & 7) << 3); }

// combined scale folded into Q: softmax(s*SCALE) == normalize(2^(s*SCALE*log2e))
#define QSC (0.17677669529663687f * 1.44269504088896341f)

// ---------------- prep ----------------
__global__ __launch_bounds__(256) void k_prep(
    const float* __restrict__ w_qkv, const float* __restrict__ w_v,
    const float* __restrict__ w_proj, const float* __restrict__ w_temp,
    const float* __restrict__ b_temp,
    u16* __restrict__ w_qt, float* __restrict__ qbias,
    u16* __restrict__ w_qkv_bf, u16* __restrict__ w_proj_bf) {
  __shared__ float wvr[256];
  __shared__ float red[256];
  int t = threadIdx.x, blk = blockIdx.x;
  if (blk < 256) {
    wvr[t] = w_v[blk * 256 + t];
    __syncthreads();
    for (int c = t; c < 512; c += 256) {
      float acc = 0.f;
      for (int m = 0; m < 256; ++m) acc += wvr[m] * w_temp[m * 512 + c];
      w_qt[blk * 512 + c] = f2bf(acc);
    }
    red[t] = wvr[t] * b_temp[t];
    __syncthreads();
    for (int s = 128; s > 0; s >>= 1) {
      if (t < s) red[t] += red[t + s];
      __syncthreads();
    }
    if (t == 0) qbias[blk] = red[0];
  } else {
    int e = (blk - 256) * 256 + t;
    if (e < 512 * 256) w_qkv_bf[e] = f2bf(w_qkv[e]);
    else {
      int e2 = e - 512 * 256;
      w_proj_bf[e2] = f2bf(w_proj[e2]);
    }
  }
}

// ---------------- tiled MFMA GEMM ----------------
// V=0 (64x64 tile):  qsmall = w_qt[256x512] x temp[b][512x256] -> f32 [b][p][o]
// V=1 (128x128):     kv = w_qkv[512x256] x x[b][256x4096] -> Kb/Vb [b][h][p][d], Vt [b][h][d][p]
// V=2 (128x128):     out = w_proj[256x256] x o_buf ([N][K] bf16) + bias + x -> f32
template <int V>
__global__ __launch_bounds__(256) void k_gemm(
    const u16* __restrict__ A, const float* __restrict__ Bf,
    const u16* __restrict__ Bh, float* __restrict__ Cf,
    u16* __restrict__ Kb, u16* __restrict__ Vb, u16* __restrict__ Vt,
    const float* __restrict__ bias, const float* __restrict__ Xres) {
  constexpr int BM = (V == 0) ? 64 : 128;
  constexpr int BN = (V == 0) ? 64 : 128;
  constexpr int N = (V == 0) ? 256 : 4096;
  constexpr int K = (V == 0) ? 512 : 256;
  constexpr int WM = BM / 2, WN = BN / 2;
  constexpr int FM = WM / 16, FN = WN / 16;
  constexpr int AE = BM * 64 / 256;  // A elems per thread
  constexpr int AR = 64 / AE;        // threads per A row
  constexpr int BE = BN / 4;         // B elems per thread (f32 path)

  const int t = threadIdx.x;
  const int lane = t & 63;
  const int wv = t >> 6;
  const int n0 = blockIdx.x * BN;
  const int m0 = blockIdx.y * BM;
  const int b = blockIdx.z;

  __shared__ __align__(16) u16 lds[(BM + BN) * 72];
  u16(*lds_a)[72] = (u16(*)[72])lds;
  u16(*lds_b)[72] = (u16(*)[72])(lds + BM * 72);

  f32x4 acc[FM][FN] = {};
  const int mq2 = (wv >> 1) * WM, nq2 = (wv & 1) * WN;
  const int lr = lane & 15, lg = lane >> 4;

  for (int k0 = 0; k0 < K; k0 += 64) {
    __syncthreads();
    {  // stage A [m][k] bf16
      int m = t / AR, c0 = (t % AR) * AE;
      const u16* src = A + (size_t)(m0 + m) * K + k0 + c0;
#pragma unroll
      for (int i = 0; i < AE / 8; ++i)
        *(u16x8*)&lds_a[m][c0 + 8 * i] = *(const u16x8*)(src + 8 * i);
    }
    if constexpr (V != 2) {  // B from f32 [K][N]: cvt + transpose into [n][k]
      int k = t >> 2, nn0 = (t & 3) * BE;
      const float* src = Bf + (size_t)b * K * N + (size_t)(k0 + k) * N + n0 + nn0;
#pragma unroll
      for (int i4 = 0; i4 < BE / 4; ++i4) {
        f32x4 v = *(const f32x4*)(src + 4 * i4);
        unsigned p0, p1;
        asm("v_cvt_pk_bf16_f32 %0, %1, %2" : "=v"(p0) : "v"(v[0]), "v"(v[1]));
        asm("v_cvt_pk_bf16_f32 %0, %1, %2" : "=v"(p1) : "v"(v[2]), "v"(v[3]));
        int n = nn0 + 4 * i4;
        lds_b[n][bswz(n, k)] = (u16)p0;
        lds_b[n + 1][bswz(n + 1, k)] = (u16)(p0 >> 16);
        lds_b[n + 2][bswz(n + 2, k)] = (u16)p1;
        lds_b[n + 3][bswz(n + 3, k)] = (u16)(p1 >> 16);
      }
    } else {  // B from bf16 [N][K]
      int n = t >> 1, c0 = (t & 1) * 32;
      const u16* src = Bh + (size_t)b * N * K + (size_t)(n0 + n) * K + k0 + c0;
#pragma unroll
      for (int i = 0; i < 4; ++i)
        *(u16x8*)&lds_b[n][bswz(n, c0 + 8 * i)] = *(const u16x8*)(src + 8 * i);
    }
    __syncthreads();
#pragma unroll
    for (int kk = 0; kk < 2; ++kk) {
      Frag af[FM], bfr[FN];
#pragma unroll
      for (int mi = 0; mi < FM; ++mi)
        af[mi].u = *(const u16x8*)&lds_a[mq2 + 16 * mi + lr][kk * 32 + 8 * lg];
#pragma unroll
      for (int ni = 0; ni < FN; ++ni) {
        int n = nq2 + 16 * ni + lr;
        bfr[ni].u = *(const u16x8*)&lds_b[n][bswz(n, kk * 32 + 8 * lg)];
      }
#pragma unroll
      for (int mi = 0; mi < FM; ++mi)
#pragma unroll
        for (int ni = 0; ni < FN; ++ni)
          acc[mi][ni] = __builtin_amdgcn_mfma_f32_16x16x32_bf16(
              af[mi].b, bfr[ni].b, acc[mi][ni], 0, 0, 0);
    }
  }

  if constexpr (V == 0) {
#pragma unroll
    for (int mi = 0; mi < FM; ++mi)
#pragma unroll
      for (int ni = 0; ni < FN; ++ni) {
        int mbase = m0 + mq2 + 16 * mi + 4 * lg;
        int n = n0 + nq2 + 16 * ni + lr;
        *(f32x4*)(Cf + ((size_t)b * 256 + n) * 256 + mbase) = acc[mi][ni];
      }
  } else if constexpr (V == 1) {
#pragma unroll
    for (int mi = 0; mi < FM; ++mi)
#pragma unroll
      for (int ni = 0; ni < FN; ++ni) {
        int mbase = m0 + mq2 + 16 * mi + 4 * lg;
        int n = n0 + nq2 + 16 * ni + lr;
        u16x4 pk;
#pragma unroll
        for (int j = 0; j < 4; ++j) pk[j] = f2bf(acc[mi][ni][j]);
        if (mbase < 256) {
          int head = mbase >> 5, d = mbase & 31;
          *(u16x4*)(Kb + ((size_t)(b * 8 + head) * 4096 + n) * 32 + d) = pk;
        } else {
          int mm = mbase - 256;
          int head = mm >> 5, d = mm & 31;
          *(u16x4*)(Vb + ((size_t)(b * 8 + head) * 4096 + n) * 32 + d) = pk;
        }
      }
    if (m0 >= 256) {  // Vt[d][p] via per-wave LDS transpose rounds
      float(*lds_t)[68] = (float(*)[68])lds;
#pragma unroll 1
      for (int r = 0; r < 4; ++r) {
        __syncthreads();
        if (wv == r) {
#pragma unroll
          for (int mi = 0; mi < FM; ++mi)
#pragma unroll
            for (int ni = 0; ni < FN; ++ni)
#pragma unroll
              for (int j = 0; j < 4; ++j)
                lds_t[16 * mi + 4 * lg + j][16 * ni + lr] = acc[mi][ni][j];
        }
        __syncthreads();
        int dloc = t >> 2, nc = (t & 3) * 16;
        int mg = (m0 - 256) + (r >> 1) * 64 + dloc;
        int head = mg >> 5, d = mg & 31;
        int ng = n0 + (r & 1) * 64 + nc;
        u16x8 o0, o1;
#pragma unroll
        for (int i = 0; i < 8; ++i) {
          o0[i] = f2bf(lds_t[dloc][nc + i]);
          o1[i] = f2bf(lds_t[dloc][nc + 8 + i]);
        }
        u16* dst = Vt + ((size_t)(b * 8 + head) * 32 + d) * 4096 + ng;
        *(u16x8*)dst = o0;
        *(u16x8*)(dst + 8) = o1;
      }
    }
  } else {
#pragma unroll
    for (int mi = 0; mi < FM; ++mi)
#pragma unroll
      for (int ni = 0; ni < FN; ++ni) {
        int mbase = m0 + mq2 + 16 * mi + 4 * lg;
        int n = n0 + nq2 + 16 * ni + lr;
#pragma unroll
        for (int j = 0; j < 4; ++j) {
          int m = mbase + j;
          size_t off = ((size_t)b * 256 + m) * 4096 + n;
          Cf[off] = acc[mi][ni][j] + bias[m] + Xres[off];
        }
      }
  }
}

// ---------------- bilinear 16x16 -> 64x64 upsample of qsmall, + qbias, * QSC ----------------
DEVFN void blc(int y, int& i0, int& i1, float& w) {
  float fy = 0.25f * y - 0.375f;
  float ff = floorf(fy);
  w = fy - ff;
  int i = (int)ff;
  i0 = i < 0 ? 0 : i;
  i1 = (i + 1 > 15) ? 15 : i + 1;
}

__global__ __launch_bounds__(256) void k_resize(
    const float* __restrict__ qsmall, const float* __restrict__ qbias,
    u16* __restrict__ Qb) {
  int gid = blockIdx.x * 256 + threadIdx.x;
  int c8 = gid & 31;
  int p = (gid >> 5) & 4095;
  int b = gid >> 17;
  int y = p >> 6, x = p & 63;
  int y0, y1, x0, x1;
  float wy, wx;
  blc(y, y0, y1, wy);
  blc(x, x0, x1, wx);
  const float* base = qsmall + (size_t)b * 65536;
  int o0 = c8 * 8;
  const float* r00 = base + (y0 * 16 + x0) * 256 + o0;
  const float* r01 = base + (y0 * 16 + x1) * 256 + o0;
  const float* r10 = base + (y1 * 16 + x0) * 256 + o0;
  const float* r11 = base + (y1 * 16 + x1) * 256 + o0;
  float w00 = (1 - wy) * (1 - wx), w01 = (1 - wy) * wx;
  float w10 = wy * (1 - wx), w11 = wy * wx;
  u16x8 outv;
#pragma unroll
  for (int i = 0; i < 8; ++i) {
    float v = w00 * r00[i] + w01 * r01[i] + w10 * r10[i] + w11 * r11[i] + qbias[o0 + i];
    outv[i] = f2bf(v * QSC);
  }
  int head = o0 >> 5, d = o0 & 31;
  *(u16x8*)(Qb + ((size_t)(b * 8 + head) * 4096 + p) * 32 + d) = outv;
}

// ---------------- MFMA attention, swapped-operand, balanced ----------------
// Blocks [0,512): head4 split-K — 4 waves share 64 queries, 256-key segments each,
//                 combine unnormalized partials in LDS.
// Blocks [512,1152): independent waves — head3 (8 chunks), head2 (2), rows (2).
__global__ __launch_bounds__(256) void k_attn(
    const u16* __restrict__ Qb, const u16* __restrict__ Kb,
    const u16* __restrict__ Vt, u16* __restrict__ Ob) {
  const int t = threadIdx.x, lane = t & 63, wv = t >> 6;
  const int lr = lane & 15, lg = lane >> 4;
  const int bid = blockIdx.x;
  const bool split = (bid < 512);

  __shared__ float sm_o[4][4][2][4][64];
  __shared__ float sm_l[4][4][16];

  int b, head, lws, i0, by, bx, j_begin, j_end;
  if (split) {
    int idx = bid;
    b = idx >> 6;
    int qg = idx & 63;
    head = 4; lws = 5;
    int w = qg >> 4;
    i0 = (qg & 15) * 64;
    by = (w >> 1) * 32;
    bx = (w & 1) * 32;
    j_begin = wv * 256;
    j_end = j_begin + 256;
  } else {
    int u = (bid - 512) * 4 + wv;
    if (u < 512) {
      head = 3; lws = 4;
      b = u >> 6;
      int qb = (u & 63) << 6;
      int w = qb >> 8;
      i0 = qb & 255;
      by = (w >> 2) * 16;
      bx = (w & 3) * 16;
      j_begin = 0; j_end = 256;
    } else if (u < 1024) {
      head = 2; lws = 3;
      int u2 = u - 512;
      b = u2 >> 6;
      int w = u2 & 63;
      i0 = 0;
      by = (w >> 3) * 8;
      bx = (w & 7) * 8;
      j_begin = 0; j_end = 64;
    } else {
      int r = u - 1024;
      b = r / 192;
      int rr = r % 192;
      head = 5 + (rr >> 6);
      lws = 6;
      by = rr & 63; bx = 0; i0 = 0;
      j_begin = 0; j_end = 64;
    }
  }
  const int wsm = (1 << lws) - 1;
  const size_t hb = (size_t)(b * 8 + head) * 131072;
  auto mapP = [&](int i) { return ((by + (i >> lws)) << 6) + bx + (i & wsm); };

  Frag qf[4];
#pragma unroll
  for (int f = 0; f < 4; ++f)
    qf[f].u = *(const u16x8*)(Qb + hb + (size_t)mapP(i0 + 16 * f + lr) * 32 + 8 * lg);

  f32x4 oT[4][2] = {};
  float lsum[4] = {0.f, 0.f, 0.f, 0.f};
  const int addrA = (32 * (lg & 1) + lr) * 4;
  const int addrB = addrA + 64;
  const bool lo_half = (lg < 2);

  auto chunk = [&](const Frag& k0, const Frag& k1, const Frag& v0, const Frag& v1) {
#pragma unroll
    for (int f = 0; f < 4; ++f) {
      f32x4 zz = {};
      f32x4 s0 = __builtin_amdgcn_mfma_f32_16x16x32_bf16(k0.b, qf[f].b, zz, 0, 0, 0);
      f32x4 s1 = __builtin_amdgcn_mfma_f32_16x16x32_bf16(k1.b, qf[f].b, zz, 0, 0, 0);
      float p[8];
#pragma unroll
      for (int j = 0; j < 4; ++j) {
        p[j] = exp2f(s0[j]);
        p[4 + j] = exp2f(s1[j]);
      }
#pragma unroll
      for (int j = 0; j < 8; ++j) lsum[f] += p[j];
      unsigned pk0, pk1, pk2, pk3;
      asm("v_cvt_pk_bf16_f32 %0, %1, %2" : "=v"(pk0) : "v"(p[0]), "v"(p[1]));
      asm("v_cvt_pk_bf16_f32 %0, %1, %2" : "=v"(pk1) : "v"(p[2]), "v"(p[3]));
      asm("v_cvt_pk_bf16_f32 %0, %1, %2" : "=v"(pk2) : "v"(p[4]), "v"(p[5]));
      asm("v_cvt_pk_bf16_f32 %0, %1, %2" : "=v"(pk3) : "v"(p[6]), "v"(p[7]));
      union { unsigned w[4]; Frag fr; } pb;
      pb.w[0] = (unsigned)__builtin_amdgcn_ds_bpermute(addrA, lo_half ? (int)pk0 : (int)pk2);
      pb.w[1] = (unsigned)__builtin_amdgcn_ds_bpermute(addrA, lo_half ? (int)pk1 : (int)pk3);
      pb.w[2] = (unsigned)__builtin_amdgcn_ds_bpermute(addrB, lo_half ? (int)pk0 : (int)pk2);
      pb.w[3] = (unsigned)__builtin_amdgcn_ds_bpermute(addrB, lo_half ? (int)pk1 : (int)pk3);
      oT[f][0] = __builtin_amdgcn_mfma_f32_16x16x32_bf16(v0.b, pb.fr.b, oT[f][0], 0, 0, 0);
      oT[f][1] = __builtin_amdgcn_mfma_f32_16x16x32_bf16(v1.b, pb.fr.b, oT[f][1], 0, 0, 0);
    }
  };

  Frag k0A, k1A, v0A, v1A, k0B, k1B, v0B, v1B;
  auto loadKV = [&](int j0, Frag& a, Frag& c, Frag& d, Frag& e) {
    a.u = *(const u16x8*)(Kb + hb + (size_t)mapP(j0 + lr) * 32 + 8 * lg);
    c.u = *(const u16x8*)(Kb + hb + (size_t)mapP(j0 + 16 + lr) * 32 + 8 * lg);
    int pv = mapP(j0 + 8 * lg);
    d.u = *(const u16x8*)(Vt + hb + (size_t)lr * 4096 + pv);
    e.u = *(const u16x8*)(Vt + hb + (size_t)(16 + lr) * 4096 + pv);
  };

  loadKV(j_begin, k0A, k1A, v0A, v1A);
  for (int j0 = j_begin; j0 < j_end; j0 += 64) {
    loadKV(j0 + 32, k0B, k1B, v0B, v1B);
    chunk(k0A, k1A, v0A, v1A);
    if (j0 + 64 < j_end) loadKV(j0 + 64, k0A, k1A, v0A, v1A);
    chunk(k0B, k1B, v0B, v1B);
  }

  if (!split) {
#pragma unroll
    for (int f = 0; f < 4; ++f) {
      float s = lsum[f];
      s += __shfl_xor(s, 16, 64);
      s += __shfl_xor(s, 32, 64);
      float inv = 1.f / s;
      int q = i0 + 16 * f + lr;
      u16x4 lo, hi;
#pragma unroll
      for (int j = 0; j < 4; ++j) {
        lo[j] = f2bf(oT[f][0][j] * inv);
        hi[j] = f2bf(oT[f][1][j] * inv);
      }
      if (head < 5) {
        int p = mapP(q);
        u16* dst = Ob + ((size_t)b * 4096 + p) * 256 + head * 32;
        *(u16x4*)(dst + 4 * lg) = lo;
        *(u16x4*)(dst + 16 + 4 * lg) = hi;
      } else {
        int n = head - 5;
        int g32 = ((n * 64 + by) << 6) + q;
        int m3 = g32 % 3, sp = g32 / 3;
        u16* dst = Ob + ((size_t)b * 4096 + sp) * 256 + 160 + 32 * m3;
        *(u16x4*)(dst + 4 * lg) = lo;
        *(u16x4*)(dst + 16 + 4 * lg) = hi;
      }
    }
  } else {
#pragma unroll
    for (int f = 0; f < 4; ++f) {
      float s = lsum[f];
      s += __shfl_xor(s, 16, 64);
      s += __shfl_xor(s, 32, 64);
      if (lg == 0) sm_l[wv][f][lr] = s;
#pragma unroll
      for (int h = 0; h < 2; ++h)
#pragma unroll
        for (int j = 0; j < 4; ++j) sm_o[wv][f][h][j][lane] = oT[f][h][j];
    }
    __syncthreads();
    int f = wv;
    float ot0[4] = {0.f, 0.f, 0.f, 0.f}, ot1[4] = {0.f, 0.f, 0.f, 0.f};
    float ls = 0.f;
#pragma unroll
    for (int w = 0; w < 4; ++w) {
      ls += sm_l[w][f][lr];
#pragma unroll
      for (int j = 0; j < 4; ++j) {
        ot0[j] += sm_o[w][f][0][j][lane];
        ot1[j] += sm_o[w][f][1][j][lane];
      }
    }
    float inv = 1.f / ls;
    int q = i0 + 16 * f + lr;
    int p = mapP(q);
    u16x4 lo, hi;
#pragma unroll
    for (int j = 0; j < 4; ++j) {
      lo[j] = f2bf(ot0[j] * inv);
      hi[j] = f2bf(ot1[j] * inv);
    }
    u16* dst = Ob + ((size_t)b * 4096 + p) * 256 + head * 32;
    *(u16x4*)(dst + 4 * lg) = lo;
    *(u16x4*)(dst + 16 + 4 * lg) = hi;
  }
}

// ---------------- scalar attention for ws=2 (head0) and ws=4 (head1) ----------------
template <int WS>
DEVFN void small_attn_one(const u16* Qb, const u16* Kb, const u16* Vb, u16* Ob,
                          int b, int head, int p) {
  constexpr int L = WS * WS;
  int y = p >> 6, x = p & 63;
  int wy0 = y & ~(WS - 1), wx0 = x & ~(WS - 1);
  const size_t hb = (size_t)(b * 8 + head) * 131072;
  float qr[32];
  const u16* qp = Qb + hb + (size_t)p * 32;
#pragma unroll
  for (int c = 0; c < 4; ++c) {
    u16x8 v = *(const u16x8*)(qp + c * 8);
#pragma unroll
    for (int i = 0; i < 8; ++i) qr[c * 8 + i] = bf2f(v[i]);
  }
  float s[L];
#pragma unroll
  for (int j = 0; j < L; ++j) {
    int kp = (wy0 + j / WS) * 64 + wx0 + (j % WS);
    const u16* kr = Kb + hb + (size_t)kp * 32;
    float acc = 0.f;
#pragma unroll
    for (int c = 0; c < 4; ++c) {
      u16x8 v = *(const u16x8*)(kr + c * 8);
#pragma unroll
      for (int i = 0; i < 8; ++i) acc += qr[c * 8 + i] * bf2f(v[i]);
    }
    s[j] = acc;
  }
  float mx = s[0];
#pragma unroll
  for (int j = 1; j < L; ++j) mx = fmaxf(mx, s[j]);
  float sum = 0.f;
#pragma unroll
  for (int j = 0; j < L; ++j) {
    s[j] = exp2f(s[j] - mx);
    sum += s[j];
  }
  float inv = 1.f / sum;
  float o[32];
#pragma unroll
  for (int i = 0; i < 32; ++i) o[i] = 0.f;
#pragma unroll
  for (int j = 0; j < L; ++j) {
    int kp = (wy0 + j / WS) * 64 + wx0 + (j % WS);
    const u16* vr = Vb + hb + (size_t)kp * 32;
    float pj = s[j] * inv;
#pragma unroll
    for (int c = 0; c < 4; ++c) {
      u16x8 v = *(const u16x8*)(vr + c * 8);
#pragma unroll
      for (int i = 0; i < 8; ++i) o[c * 8 + i] += pj * bf2f(v[i]);
    }
  }
  u16* dst = Ob + ((size_t)b * 4096 + p) * 256 + head * 32;
#pragma unroll
  for (int c = 0; c < 4; ++c) {
    u16x8 v;
#pragma unroll
    for (int i = 0; i < 8; ++i) v[i] = f2bf(o[c * 8 + i]);
    *(u16x8*)(dst + c * 8) = v;
  }
}

__global__ __launch_bounds__(256) void k_attn_small(
    const u16* __restrict__ Qb, const u16* __restrict__ Kb,
    const u16* __restrict__ Vb, u16* __restrict__ Ob) {
  int gid = blockIdx.x * 256 + threadIdx.x;
  int head = gid >> 15;
  int idx = gid & 32767;
  int b = idx >> 12, p = idx & 4095;
  if (head == 0) small_attn_one<2>(Qb, Kb, Vb, Ob, b, 0, p);
  else small_attn_one<4>(Qb, Kb, Vb, Ob, b, 1, p);
}

extern "C" void kernel_launch(void* const* d_in, const int* in_sizes, int n_in,
                              void* d_out, int out_size, void* d_ws, size_t ws_size,
                              hipStream_t stream) {
  const float* x = (const float*)d_in[0];
  const float* temp = (const float*)d_in[1];
  const float* w_qkv = (const float*)d_in[2];
  const float* w_v = (const float*)d_in[3];
  const float* w_proj = (const float*)d_in[4];
  const float* b_proj = (const float*)d_in[5];
  const float* w_temp = (const float*)d_in[6];
  const float* b_temp = (const float*)d_in[7];
  (void)in_sizes; (void)n_in; (void)out_size; (void)ws_size;

  char* ws = (char*)d_ws;
  u16* w_qt = (u16*)(ws + 0);              // 262144 B
  u16* w_qkv_bf = (u16*)(ws + 262144);     // 262144 B
  u16* w_proj_bf = (u16*)(ws + 524288);    // 131072 B
  float* qbias = (float*)(ws + 655360);    // 1024 B
  float* qsmall = (float*)(ws + 656384);   // 2097152 B  [b][p16][o]
  u16* q_buf = (u16*)(ws + 2753536);       // 16777216 B [b][h][p][d]
  u16* k_buf = (u16*)(ws + 19530752);      // 16777216 B [b][h][p][d]
  u16* v_buf = (u16*)(ws + 36307968);      // 16777216 B [b][h][p][d]
  u16* v_t = (u16*)(ws + 53085184);        // 16777216 B [b][h][d][p]
  u16* o_buf = (u16*)(ws + 69862400);      // 16777216 B [b][p][c]
  float* out = (float*)d_out;

  k_prep<<<1024, 256, 0, stream>>>(w_qkv, w_v, w_proj, w_temp, b_temp,
                                   w_qt, qbias, w_qkv_bf, w_proj_bf);
  k_gemm<0><<<dim3(4, 4, 8), 256, 0, stream>>>(w_qt, temp, nullptr, qsmall,
                                               nullptr, nullptr, nullptr, nullptr, nullptr);
  k_resize<<<4096, 256, 0, stream>>>(qsmall, qbias, q_buf);
  k_gemm<1><<<dim3(32, 4, 8), 256, 0, stream>>>(w_qkv_bf, x, nullptr, nullptr,
                                                k_buf, v_buf, v_t, nullptr, nullptr);
  k_attn<<<1152, 256, 0, stream>>>(q_buf, k_buf, v_t, o_buf);
  k_attn_small<<<256, 256, 0, stream>>>(q_buf, k_buf, v_buf, o_buf);
  k_gemm<2><<<dim3(32, 2, 8), 256, 0, stream>>>(w_proj_bf, nullptr, o_buf, out,
                                                nullptr, nullptr, nullptr, b_proj, x);
}

// Round 5
// 121.734 us; speedup vs baseline: 1.2936x; 1.2936x over previous
//
#include <hip/hip_runtime.h>

typedef unsigned short u16;
typedef float f32x4 __attribute__((ext_vector_type(4)));
typedef unsigned short u16x8 __attribute__((ext_vector_type(8)));
typedef unsigned short u16x4 __attribute__((ext_vector_type(4)));
typedef __bf16 bf16x8 __attribute__((ext_vector_type(8)));

union Frag { u16x8 u; bf16x8 b; };
union Frag44 { u16x4 h[2]; u16x8 u; bf16x8 b; };

#define DEVFN static __device__ __forceinline__

DEVFN u16 f2bf(float f) {
  unsigned u = __builtin_bit_cast(unsigned, f);
  u += 0x7FFFu + ((u >> 16) & 1u);
  return (u16)(u >> 16);
}
DEVFN float bf2f(u16 h) {
  return __builtin_bit_cast(float, ((unsigned)h) << 16);
}
DEVFN int bswz(int n, int k) { return k ^ ((((n >> 4) ^ n) & 7) << 3); }

// combined scale folded into Q: softmax(s*SCALE) == normalize(2^(s*SCALE*log2e))
#define QSC (0.17677669529663687f * 1.44269504088896341f)

// ---------------- prep ----------------
__global__ __launch_bounds__(256) void k_prep(
    const float* __restrict__ w_qkv, const float* __restrict__ w_v,
    const float* __restrict__ w_proj, const float* __restrict__ w_temp,
    const float* __restrict__ b_temp,
    u16* __restrict__ w_qt, float* __restrict__ qbias,
    u16* __restrict__ w_qkv_bf, u16* __restrict__ w_proj_bf) {
  __shared__ float wvr[256];
  __shared__ float red[256];
  int t = threadIdx.x, blk = blockIdx.x;
  if (blk < 256) {
    wvr[t] = w_v[blk * 256 + t];
    __syncthreads();
    for (int c = t; c < 512; c += 256) {
      float acc = 0.f;
      for (int m = 0; m < 256; ++m) acc += wvr[m] * w_temp[m * 512 + c];
      w_qt[blk * 512 + c] = f2bf(acc);
    }
    red[t] = wvr[t] * b_temp[t];
    __syncthreads();
    for (int s = 128; s > 0; s >>= 1) {
      if (t < s) red[t] += red[t + s];
      __syncthreads();
    }
    if (t == 0) qbias[blk] = red[0];
  } else {
    int e = (blk - 256) * 256 + t;
    if (e < 512 * 256) w_qkv_bf[e] = f2bf(w_qkv[e]);
    else {
      int e2 = e - 512 * 256;
      w_proj_bf[e2] = f2bf(w_proj[e2]);
    }
  }
}

// ---------------- x transpose+cvt: [b][c=256][p=4096] f32 -> [b][p][c] bf16 ----------------
__global__ __launch_bounds__(256) void k_xt(
    const float* __restrict__ x, u16* __restrict__ xt) {
  __shared__ float lds[64][65];
  int t = threadIdx.x, bid = blockIdx.x;
  int b = bid >> 8, rem = bid & 255;
  int c0 = (rem >> 6) << 6;
  int p0 = (rem & 63) << 6;
  int cr = t >> 2, pc = (t & 3) * 16;
  const float* src = x + (size_t)(b * 256 + c0 + cr) * 4096 + p0 + pc;
#pragma unroll
  for (int i = 0; i < 4; ++i) {
    f32x4 v = *(const f32x4*)(src + 4 * i);
#pragma unroll
    for (int j = 0; j < 4; ++j) lds[cr][pc + 4 * i + j] = v[j];
  }
  __syncthreads();
  int pr = t >> 2, cq = (t & 3) * 16;
  u16x8 o0, o1;
#pragma unroll
  for (int j = 0; j < 8; ++j) {
    o0[j] = f2bf(lds[cq + j][pr]);
    o1[j] = f2bf(lds[cq + 8 + j][pr]);
  }
  u16* dst = xt + ((size_t)(b * 4096) + p0 + pr) * 256 + c0 + cq;
  *(u16x8*)dst = o0;
  *(u16x8*)(dst + 8) = o1;
}

// ---------------- 64x64-tile MFMA GEMM ----------------
// V=0: qsmall = w_qt[256x512] x temp[b][512x256] (f32 B) -> f32 [b][p][o]
// V=1: kv = w_qkv[512x256] x x_t ([N][K] bf16) -> Kb/Vb [b][h][p][d], Vt [b][h][d][p]
// V=2: out = w_proj[256x256] x o_buf ([N][K] bf16) + bias + x -> f32
template <int V>
__global__ __launch_bounds__(256) void k_gemm(
    const u16* __restrict__ A, const float* __restrict__ Bf,
    const u16* __restrict__ Bh, float* __restrict__ Cf,
    u16* __restrict__ Kb, u16* __restrict__ Vb, u16* __restrict__ Vt,
    const float* __restrict__ bias, const float* __restrict__ Xres) {
  constexpr int N = (V == 0) ? 256 : 4096;
  constexpr int K = (V == 0) ? 512 : 256;

  const int t = threadIdx.x;
  const int lane = t & 63;
  const int wv = t >> 6;
  const int n0 = blockIdx.x * 64;
  const int m0 = blockIdx.y * 64;
  const int b = blockIdx.z;

  __shared__ __align__(16) u16 lds[2 * 64 * 72];
  u16(*lds_a)[72] = (u16(*)[72])lds;
  u16(*lds_b)[72] = (u16(*)[72])(lds + 64 * 72);

  f32x4 acc[2][2] = {};
  const int mq = (wv >> 1) * 32, nq = (wv & 1) * 32;
  const int lr = lane & 15, lg = lane >> 4;

  for (int k0 = 0; k0 < K; k0 += 64) {
    __syncthreads();
    {  // stage A [m][k]
      int m = t >> 2, c0 = (t & 3) * 16;
      const u16* src = A + (size_t)(m0 + m) * K + k0 + c0;
      *(u16x8*)&lds_a[m][c0] = *(const u16x8*)src;
      *(u16x8*)&lds_a[m][c0 + 8] = *(const u16x8*)(src + 8);
    }
    if constexpr (V == 0) {  // B from f32 [K][N] source -> lds_b[n][k] (cvt+transpose)
      int k = t >> 2, nn0 = (t & 3) * 16;
      const float* src = Bf + (size_t)b * K * N + (size_t)(k0 + k) * N + n0 + nn0;
#pragma unroll
      for (int i4 = 0; i4 < 4; ++i4) {
        f32x4 v = *(const f32x4*)(src + i4 * 4);
#pragma unroll
        for (int j = 0; j < 4; ++j) {
          int n = nn0 + i4 * 4 + j;
          lds_b[n][bswz(n, k)] = f2bf(v[j]);
        }
      }
    } else {  // B from bf16 [N][K] source
      int n = t >> 2, c0 = (t & 3) * 16;
      const u16* src = Bh + (size_t)b * N * K + (size_t)(n0 + n) * K + k0 + c0;
      u16x8 v0 = *(const u16x8*)src, v1 = *(const u16x8*)(src + 8);
      *(u16x8*)&lds_b[n][bswz(n, c0)] = v0;
      *(u16x8*)&lds_b[n][bswz(n, c0 + 8)] = v1;
    }
    __syncthreads();
#pragma unroll
    for (int kk = 0; kk < 2; ++kk) {
      Frag af[2], bfr[2];
#pragma unroll
      for (int i = 0; i < 2; ++i) {
        af[i].u = *(const u16x8*)&lds_a[mq + 16 * i + lr][kk * 32 + 8 * lg];
        int n = nq + 16 * i + lr;
        bfr[i].u = *(const u16x8*)&lds_b[n][bswz(n, kk * 32 + 8 * lg)];
      }
#pragma unroll
      for (int mi = 0; mi < 2; ++mi)
#pragma unroll
        for (int ni = 0; ni < 2; ++ni)
          acc[mi][ni] = __builtin_amdgcn_mfma_f32_16x16x32_bf16(
              af[mi].b, bfr[ni].b, acc[mi][ni], 0, 0, 0);
    }
  }

  if constexpr (V == 0) {
#pragma unroll
    for (int mi = 0; mi < 2; ++mi)
#pragma unroll
      for (int ni = 0; ni < 2; ++ni) {
        int mbase = m0 + mq + 16 * mi + 4 * lg;
        int n = n0 + nq + 16 * ni + lr;
        *(f32x4*)(Cf + ((size_t)b * 256 + n) * 256 + mbase) = acc[mi][ni];
      }
  } else if constexpr (V == 1) {
#pragma unroll
    for (int mi = 0; mi < 2; ++mi)
#pragma unroll
      for (int ni = 0; ni < 2; ++ni) {
        int mbase = m0 + mq + 16 * mi + 4 * lg;
        int n = n0 + nq + 16 * ni + lr;
        u16x4 pk;
#pragma unroll
        for (int j = 0; j < 4; ++j) pk[j] = f2bf(acc[mi][ni][j]);
        if (mbase < 256) {
          int head = mbase >> 5, d = mbase & 31;
          *(u16x4*)(Kb + ((size_t)(b * 8 + head) * 4096 + n) * 32 + d) = pk;
        } else {
          int mm = mbase - 256;
          int head = mm >> 5, d = mm & 31;
          *(u16x4*)(Vb + ((size_t)(b * 8 + head) * 4096 + n) * 32 + d) = pk;
        }
      }
    if (m0 >= 256) {  // also produce v_t[d][p] via LDS transpose
      __syncthreads();
      float(*lds_t)[68] = (float(*)[68])lds;
#pragma unroll
      for (int mi = 0; mi < 2; ++mi)
#pragma unroll
        for (int ni = 0; ni < 2; ++ni)
#pragma unroll
          for (int j = 0; j < 4; ++j)
            lds_t[mq + 16 * mi + 4 * lg + j][nq + 16 * ni + lr] = acc[mi][ni][j];
      __syncthreads();
      int dloc = t >> 2, nc = (t & 3) * 16;
      int head = ((m0 - 256) >> 5) + (dloc >> 5), d = dloc & 31;
      u16x8 o0, o1;
#pragma unroll
      for (int i = 0; i < 8; ++i) {
        o0[i] = f2bf(lds_t[dloc][nc + i]);
        o1[i] = f2bf(lds_t[dloc][nc + 8 + i]);
      }
      u16* dst = Vt + ((size_t)(b * 8 + head) * 32 + d) * 4096 + n0 + nc;
      *(u16x8*)dst = o0;
      *(u16x8*)(dst + 8) = o1;
    }
  } else {
#pragma unroll
    for (int mi = 0; mi < 2; ++mi)
#pragma unroll
      for (int ni = 0; ni < 2; ++ni) {
        int mbase = m0 + mq + 16 * mi + 4 * lg;
        int n = n0 + nq + 16 * ni + lr;
#pragma unroll
        for (int j = 0; j < 4; ++j) {
          int m = mbase + j;
          size_t off = ((size_t)b * 256 + m) * 4096 + n;
          Cf[off] = acc[mi][ni][j] + bias[m] + Xres[off];
        }
      }
  }
}

// ---------------- bilinear 16x16 -> 64x64 upsample of qsmall, + qbias, * QSC ----------------
DEVFN void blc(int y, int& i0, int& i1, float& w) {
  float fy = 0.25f * y - 0.375f;
  float ff = floorf(fy);
  w = fy - ff;
  int i = (int)ff;
  i0 = i < 0 ? 0 : i;
  i1 = (i + 1 > 15) ? 15 : i + 1;
}

__global__ __launch_bounds__(256) void k_resize(
    const float* __restrict__ qsmall, const float* __restrict__ qbias,
    u16* __restrict__ Qb) {
  int gid = blockIdx.x * 256 + threadIdx.x;
  int c8 = gid & 31;
  int p = (gid >> 5) & 4095;
  int b = gid >> 17;
  int y = p >> 6, x = p & 63;
  int y0, y1, x0, x1;
  float wy, wx;
  blc(y, y0, y1, wy);
  blc(x, x0, x1, wx);
  const float* base = qsmall + (size_t)b * 65536;
  int o0 = c8 * 8;
  const float* r00 = base + (y0 * 16 + x0) * 256 + o0;
  const float* r01 = base + (y0 * 16 + x1) * 256 + o0;
  const float* r10 = base + (y1 * 16 + x0) * 256 + o0;
  const float* r11 = base + (y1 * 16 + x1) * 256 + o0;
  float w00 = (1 - wy) * (1 - wx), w01 = (1 - wy) * wx;
  float w10 = wy * (1 - wx), w11 = wy * wx;
  u16x8 outv;
#pragma unroll
  for (int i = 0; i < 8; ++i) {
    float v = w00 * r00[i] + w01 * r01[i] + w10 * r10[i] + w11 * r11[i] + qbias[o0 + i];
    outv[i] = f2bf(v * QSC);
  }
  int head = o0 >> 5, d = o0 & 31;
  *(u16x8*)(Qb + ((size_t)(b * 8 + head) * 4096 + p) * 32 + d) = outv;
}

// ---------------- MFMA attention ----------------
// Blocks [0,512): head4 split-K (4 waves share 64 queries, 256-key segments).
// Blocks [512,1280): waves u = (bid-512)*4+wv:
//   u<512 head3, u<1024 head2, u<2560 row-heads (1536 waves), u>=2560 ws4 head1 (512).
__global__ __launch_bounds__(256) void k_attn(
    const u16* __restrict__ Qb, const u16* __restrict__ Kb,
    const u16* __restrict__ Vt, u16* __restrict__ Ob) {
  const int t = threadIdx.x, lane = t & 63, wv = t >> 6;
  const int lr = lane & 15, lg = lane >> 4;
  const int bid = blockIdx.x;
  const bool split = (bid < 512);

  __shared__ float sm_o[4][4][2][4][64];
  __shared__ float sm_l[4][4][16];

  const int addrA = (32 * (lg & 1) + lr) * 4;
  const int addrB = addrA + 64;
  const bool lo_half = (lg < 2);

  int b, head, lws, i0, by, bx, j_begin, j_end;
  if (split) {
    int idx = bid;
    b = idx >> 6;
    int qg = idx & 63;
    head = 4; lws = 5;
    int w = qg >> 4;
    i0 = (qg & 15) * 64;
    by = (w >> 1) * 32;
    bx = (w & 1) * 32;
    j_begin = wv * 256;
    j_end = j_begin + 256;
  } else {
    int u = (bid - 512) * 4 + wv;
    if (u >= 2560) {  // ---- ws=4 (head 1) MFMA path ----
      int r = u - 2560;
      int b4 = r >> 6;
      int qw = r & 63;
      const size_t hb1 = (size_t)(b4 * 8 + 1) * 131072;
      const u16* vb0 = Vt + hb1 + (size_t)lr * 4096;
      const u16* vb1 = Vt + hb1 + (size_t)(16 + lr) * 4096;
#pragma unroll
      for (int f = 0; f < 4; ++f) {
        int w = qw * 4 + f;
        int pbase = ((w >> 4) << 8) + ((w & 15) << 2);
        int posq = pbase + ((lr >> 2) << 6) + (lr & 3);
        Frag qf4, kf4;
        qf4.u = *(const u16x8*)(Qb + hb1 + (size_t)posq * 32 + 8 * lg);
        kf4.u = *(const u16x8*)(Kb + hb1 + (size_t)posq * 32 + 8 * lg);
        int a1 = pbase + 2 * lg * 64;
        Frag44 v0u, v1u;
        v0u.h[0] = *(const u16x4*)(vb0 + a1);
        v0u.h[1] = *(const u16x4*)(vb0 + a1 + 64);
        v1u.h[0] = *(const u16x4*)(vb1 + a1);
        v1u.h[1] = *(const u16x4*)(vb1 + a1 + 64);
        f32x4 zz = {};
        f32x4 s0 = __builtin_amdgcn_mfma_f32_16x16x32_bf16(kf4.b, qf4.b, zz, 0, 0, 0);
        float p[4];
        float ls = 0.f;
#pragma unroll
        for (int j = 0; j < 4; ++j) {
          p[j] = exp2f(s0[j]);
          ls += p[j];
        }
        unsigned pk0, pk1;
        const unsigned pk2 = 0, pk3 = 0;
        asm("v_cvt_pk_bf16_f32 %0, %1, %2" : "=v"(pk0) : "v"(p[0]), "v"(p[1]));
        asm("v_cvt_pk_bf16_f32 %0, %1, %2" : "=v"(pk1) : "v"(p[2]), "v"(p[3]));
        union { unsigned w[4]; Frag fr; } pb;
        pb.w[0] = (unsigned)__builtin_amdgcn_ds_bpermute(addrA, lo_half ? (int)pk0 : (int)pk2);
        pb.w[1] = (unsigned)__builtin_amdgcn_ds_bpermute(addrA, lo_half ? (int)pk1 : (int)pk3);
        pb.w[2] = (unsigned)__builtin_amdgcn_ds_bpermute(addrB, lo_half ? (int)pk0 : (int)pk2);
        pb.w[3] = (unsigned)__builtin_amdgcn_ds_bpermute(addrB, lo_half ? (int)pk1 : (int)pk3);
        f32x4 o0 = {}, o1 = {};
        o0 = __builtin_amdgcn_mfma_f32_16x16x32_bf16(v0u.b, pb.fr.b, o0, 0, 0, 0);
        o1 = __builtin_amdgcn_mfma_f32_16x16x32_bf16(v1u.b, pb.fr.b, o1, 0, 0, 0);
        ls += __shfl_xor(ls, 16, 64);
        ls += __shfl_xor(ls, 32, 64);
        float inv = 1.f / ls;
        u16x4 lo4, hi4;
#pragma unroll
        for (int j = 0; j < 4; ++j) {
          lo4[j] = f2bf(o0[j] * inv);
          hi4[j] = f2bf(o1[j] * inv);
        }
        u16* dst = Ob + ((size_t)b4 * 4096 + posq) * 256 + 32;
        *(u16x4*)(dst + 4 * lg) = lo4;
        *(u16x4*)(dst + 16 + 4 * lg) = hi4;
      }
      return;
    }
    if (u < 512) {
      head = 3; lws = 4;
      b = u >> 6;
      int qb = (u & 63) << 6;
      int w = qb >> 8;
      i0 = qb & 255;
      by = (w >> 2) * 16;
      bx = (w & 3) * 16;
      j_begin = 0; j_end = 256;
    } else if (u < 1024) {
      head = 2; lws = 3;
      int u2 = u - 512;
      b = u2 >> 6;
      int w = u2 & 63;
      i0 = 0;
      by = (w >> 3) * 8;
      bx = (w & 7) * 8;
      j_begin = 0; j_end = 64;
    } else {
      int r = u - 1024;
      b = r / 192;
      int rr = r % 192;
      head = 5 + (rr >> 6);
      lws = 6;
      by = rr & 63; bx = 0; i0 = 0;
      j_begin = 0; j_end = 64;
    }
  }
  const int wsm = (1 << lws) - 1;
  const size_t hb = (size_t)(b * 8 + head) * 131072;
  auto mapP = [&](int i) { return ((by + (i >> lws)) << 6) + bx + (i & wsm); };

  Frag qf[4];
#pragma unroll
  for (int f = 0; f < 4; ++f)
    qf[f].u = *(const u16x8*)(Qb + hb + (size_t)mapP(i0 + 16 * f + lr) * 32 + 8 * lg);

  f32x4 oT[4][2] = {};
  float lsum[4] = {0.f, 0.f, 0.f, 0.f};

  auto chunk = [&](const Frag& k0, const Frag& k1, const Frag& v0, const Frag& v1) {
#pragma unroll
    for (int f = 0; f < 4; ++f) {
      f32x4 zz = {};
      f32x4 s0 = __builtin_amdgcn_mfma_f32_16x16x32_bf16(k0.b, qf[f].b, zz, 0, 0, 0);
      f32x4 s1 = __builtin_amdgcn_mfma_f32_16x16x32_bf16(k1.b, qf[f].b, zz, 0, 0, 0);
      float p[8];
#pragma unroll
      for (int j = 0; j < 4; ++j) {
        p[j] = exp2f(s0[j]);
        p[4 + j] = exp2f(s1[j]);
      }
#pragma unroll
      for (int j = 0; j < 8; ++j) lsum[f] += p[j];
      unsigned pk0, pk1, pk2, pk3;
      asm("v_cvt_pk_bf16_f32 %0, %1, %2" : "=v"(pk0) : "v"(p[0]), "v"(p[1]));
      asm("v_cvt_pk_bf16_f32 %0, %1, %2" : "=v"(pk1) : "v"(p[2]), "v"(p[3]));
      asm("v_cvt_pk_bf16_f32 %0, %1, %2" : "=v"(pk2) : "v"(p[4]), "v"(p[5]));
      asm("v_cvt_pk_bf16_f32 %0, %1, %2" : "=v"(pk3) : "v"(p[6]), "v"(p[7]));
      union { unsigned w[4]; Frag fr; } pb;
      pb.w[0] = (unsigned)__builtin_amdgcn_ds_bpermute(addrA, lo_half ? (int)pk0 : (int)pk2);
      pb.w[1] = (unsigned)__builtin_amdgcn_ds_bpermute(addrA, lo_half ? (int)pk1 : (int)pk3);
      pb.w[2] = (unsigned)__builtin_amdgcn_ds_bpermute(addrB, lo_half ? (int)pk0 : (int)pk2);
      pb.w[3] = (unsigned)__builtin_amdgcn_ds_bpermute(addrB, lo_half ? (int)pk1 : (int)pk3);
      oT[f][0] = __builtin_amdgcn_mfma_f32_16x16x32_bf16(v0.b, pb.fr.b, oT[f][0], 0, 0, 0);
      oT[f][1] = __builtin_amdgcn_mfma_f32_16x16x32_bf16(v1.b, pb.fr.b, oT[f][1], 0, 0, 0);
    }
  };

  Frag k0A, k1A, v0A, v1A, k0B, k1B, v0B, v1B;
  auto loadKV = [&](int j0, Frag& a, Frag& c, Frag& d, Frag& e) {
    a.u = *(const u16x8*)(Kb + hb + (size_t)mapP(j0 + lr) * 32 + 8 * lg);
    c.u = *(const u16x8*)(Kb + hb + (size_t)mapP(j0 + 16 + lr) * 32 + 8 * lg);
    int pv = mapP(j0 + 8 * lg);
    d.u = *(const u16x8*)(Vt + hb + (size_t)lr * 4096 + pv);
    e.u = *(const u16x8*)(Vt + hb + (size_t)(16 + lr) * 4096 + pv);
  };

  loadKV(j_begin, k0A, k1A, v0A, v1A);
  for (int j0 = j_begin; j0 < j_end; j0 += 64) {
    loadKV(j0 + 32, k0B, k1B, v0B, v1B);
    chunk(k0A, k1A, v0A, v1A);
    if (j0 + 64 < j_end) loadKV(j0 + 64, k0A, k1A, v0A, v1A);
    chunk(k0B, k1B, v0B, v1B);
  }

  if (!split) {
#pragma unroll
    for (int f = 0; f < 4; ++f) {
      float s = lsum[f];
      s += __shfl_xor(s, 16, 64);
      s += __shfl_xor(s, 32, 64);
      float inv = 1.f / s;
      int q = i0 + 16 * f + lr;
      u16x4 lo, hi;
#pragma unroll
      for (int j = 0; j < 4; ++j) {
        lo[j] = f2bf(oT[f][0][j] * inv);
        hi[j] = f2bf(oT[f][1][j] * inv);
      }
      if (head < 5) {
        int p = mapP(q);
        u16* dst = Ob + ((size_t)b * 4096 + p) * 256 + head * 32;
        *(u16x4*)(dst + 4 * lg) = lo;
        *(u16x4*)(dst + 16 + 4 * lg) = hi;
      } else {
        int n = head - 5;
        int g32 = ((n * 64 + by) << 6) + q;
        int m3 = g32 % 3, sp = g32 / 3;
        u16* dst = Ob + ((size_t)b * 4096 + sp) * 256 + 160 + 32 * m3;
        *(u16x4*)(dst + 4 * lg) = lo;
        *(u16x4*)(dst + 16 + 4 * lg) = hi;
      }
    }
  } else {
#pragma unroll
    for (int f = 0; f < 4; ++f) {
      float s = lsum[f];
      s += __shfl_xor(s, 16, 64);
      s += __shfl_xor(s, 32, 64);
      if (lg == 0) sm_l[wv][f][lr] = s;
#pragma unroll
      for (int h = 0; h < 2; ++h)
#pragma unroll
        for (int j = 0; j < 4; ++j) sm_o[wv][f][h][j][lane] = oT[f][h][j];
    }
    __syncthreads();
    int f = wv;
    float ot0[4] = {0.f, 0.f, 0.f, 0.f}, ot1[4] = {0.f, 0.f, 0.f, 0.f};
    float ls = 0.f;
#pragma unroll
    for (int w = 0; w < 4; ++w) {
      ls += sm_l[w][f][lr];
#pragma unroll
      for (int j = 0; j < 4; ++j) {
        ot0[j] += sm_o[w][f][0][j][lane];
        ot1[j] += sm_o[w][f][1][j][lane];
      }
    }
    float inv = 1.f / ls;
    int q = i0 + 16 * f + lr;
    int p = mapP(q);
    u16x4 lo, hi;
#pragma unroll
    for (int j = 0; j < 4; ++j) {
      lo[j] = f2bf(ot0[j] * inv);
      hi[j] = f2bf(ot1[j] * inv);
    }
    u16* dst = Ob + ((size_t)b * 4096 + p) * 256 + head * 32;
    *(u16x4*)(dst + 4 * lg) = lo;
    *(u16x4*)(dst + 16 + 4 * lg) = hi;
  }
}

// ---------------- scalar attention for ws=2 (head0) ----------------
__global__ __launch_bounds__(256) void k_attn_small(
    const u16* __restrict__ Qb, const u16* __restrict__ Kb,
    const u16* __restrict__ Vb, u16* __restrict__ Ob) {
  int gid = blockIdx.x * 256 + threadIdx.x;
  int b = gid >> 12, p = gid & 4095;
  constexpr int WS = 2, L = 4;
  int y = p >> 6, x = p & 63;
  int wy0 = y & ~(WS - 1), wx0 = x & ~(WS - 1);
  const size_t hb = (size_t)(b * 8 + 0) * 131072;
  float qr[32];
  const u16* qp = Qb + hb + (size_t)p * 32;
#pragma unroll
  for (int c = 0; c < 4; ++c) {
    u16x8 v = *(const u16x8*)(qp + c * 8);
#pragma unroll
    for (int i = 0; i < 8; ++i) qr[c * 8 + i] = bf2f(v[i]);
  }
  float s[L];
#pragma unroll
  for (int j = 0; j < L; ++j) {
    int kp = (wy0 + j / WS) * 64 + wx0 + (j % WS);
    const u16* kr = Kb + hb + (size_t)kp * 32;
    float acc = 0.f;
#pragma unroll
    for (int c = 0; c < 4; ++c) {
      u16x8 v = *(const u16x8*)(kr + c * 8);
#pragma unroll
      for (int i = 0; i < 8; ++i) acc += qr[c * 8 + i] * bf2f(v[i]);
    }
    s[j] = acc;
  }
  float mx = s[0];
#pragma unroll
  for (int j = 1; j < L; ++j) mx = fmaxf(mx, s[j]);
  float sum = 0.f;
#pragma unroll
  for (int j = 0; j < L; ++j) {
    s[j] = exp2f(s[j] - mx);
    sum += s[j];
  }
  float inv = 1.f / sum;
  float o[32];
#pragma unroll
  for (int i = 0; i < 32; ++i) o[i] = 0.f;
#pragma unroll
  for (int j = 0; j < L; ++j) {
    int kp = (wy0 + j / WS) * 64 + wx0 + (j % WS);
    const u16* vr = Vb + hb + (size_t)kp * 32;
    float pj = s[j] * inv;
#pragma unroll
    for (int c = 0; c < 4; ++c) {
      u16x8 v = *(const u16x8*)(vr + c * 8);
#pragma unroll
      for (int i = 0; i < 8; ++i) o[c * 8 + i] += pj * bf2f(v[i]);
    }
  }
  u16* dst = Ob + ((size_t)b * 4096 + p) * 256;
#pragma unroll
  for (int c = 0; c < 4; ++c) {
    u16x8 v;
#pragma unroll
    for (int i = 0; i < 8; ++i) v[i] = f2bf(o[c * 8 + i]);
    *(u16x8*)(dst + c * 8) = v;
  }
}

extern "C" void kernel_launch(void* const* d_in, const int* in_sizes, int n_in,
                              void* d_out, int out_size, void* d_ws, size_t ws_size,
                              hipStream_t stream) {
  const float* x = (const float*)d_in[0];
  const float* temp = (const float*)d_in[1];
  const float* w_qkv = (const float*)d_in[2];
  const float* w_v = (const float*)d_in[3];
  const float* w_proj = (const float*)d_in[4];
  const float* b_proj = (const float*)d_in[5];
  const float* w_temp = (const float*)d_in[6];
  const float* b_temp = (const float*)d_in[7];
  (void)in_sizes; (void)n_in; (void)out_size; (void)ws_size;

  char* ws = (char*)d_ws;
  u16* w_qt = (u16*)(ws + 0);              // 262144 B
  u16* w_qkv_bf = (u16*)(ws + 262144);     // 262144 B
  u16* w_proj_bf = (u16*)(ws + 524288);    // 131072 B
  float* qbias = (float*)(ws + 655360);    // 1024 B
  float* qsmall = (float*)(ws + 656384);   // 2097152 B  [b][p16][o]
  u16* q_buf = (u16*)(ws + 2753536);       // 16777216 B [b][h][p][d]
  u16* k_buf = (u16*)(ws + 19530752);      // 16777216 B [b][h][p][d]
  u16* v_buf = (u16*)(ws + 36307968);      // 16777216 B [b][h][p][d]
  u16* v_t = (u16*)(ws + 53085184);        // 16777216 B [b][h][d][p]
  u16* o_buf = (u16*)(ws + 69862400);      // 16777216 B [b][p][c]  (aliased: x_t before attn)
  u16* x_t = o_buf;                        // [b][p][c] bf16 — dead before o_buf written
  float* out = (float*)d_out;

  k_prep<<<1024, 256, 0, stream>>>(w_qkv, w_v, w_proj, w_temp, b_temp,
                                   w_qt, qbias, w_qkv_bf, w_proj_bf);
  k_xt<<<2048, 256, 0, stream>>>(x, x_t);
  k_gemm<0><<<dim3(4, 4, 8), 256, 0, stream>>>(w_qt, temp, nullptr, qsmall,
                                               nullptr, nullptr, nullptr, nullptr, nullptr);
  k_resize<<<4096, 256, 0, stream>>>(qsmall, qbias, q_buf);
  k_gemm<1><<<dim3(64, 8, 8), 256, 0, stream>>>(w_qkv_bf, nullptr, x_t, nullptr,
                                                k_buf, v_buf, v_t, nullptr, nullptr);
  k_attn<<<1280, 256, 0, stream>>>(q_buf, k_buf, v_t, o_buf);
  k_attn_small<<<128, 256, 0, stream>>>(q_buf, k_buf, v_buf, o_buf);
  k_gemm<2><<<dim3(64, 4, 8), 256, 0, stream>>>(w_proj_bf, nullptr, o_buf, out,
                                                nullptr, nullptr, nullptr, b_proj, x);
}